// Round 9
// baseline (240.642 us; speedup 1.0000x reference)
//
#include <hip/hip_runtime.h>
#include <hip/hip_bf16.h>

// Problem constants (ConvBertSelfAttention): B=4, S=2048, H=8, D=64, K=9
#define NH   8
#define HD   64
#define KW   9
#define AD   512      // H*D
#define HIDD 1024     // 2*A
#define BB   4
#define SS   2048
#define MTOK (BB*SS)  // 8192 tokens
#define WSZ  262144   // 512*512 weight elements

typedef __attribute__((ext_vector_type(8))) short short8;   // 8 bf16 (4 VGPRs)
typedef __attribute__((ext_vector_type(4))) float floatx4;  // MFMA C/D

__device__ __forceinline__ short f2bf(float f) {
    unsigned u = __float_as_uint(f);
    u = (u + 0x7FFFu + ((u >> 16) & 1u)) >> 16;
    return (short)u;
}
__device__ __forceinline__ float bf2f(short s) {
    return __uint_as_float(((unsigned)(unsigned short)s) << 16);
}
// raw v_exp_f32 (2^x)
__device__ __forceinline__ float exp2_raw(float x) {
    return __builtin_amdgcn_exp2f(x);
}
// pack two floats to two bf16 (round-half-up, one v_perm_b32)
__device__ __forceinline__ unsigned pkbf2(float a, float b) {
    unsigned au = __float_as_uint(a) + 0x8000u;
    unsigned bu = __float_as_uint(b) + 0x8000u;
    return __builtin_amdgcn_perm(bu, au, 0x07060302);
}
// async global->LDS, 16 B per lane; LDS dest = wave-uniform base + lane*16
__device__ __forceinline__ void gl2lds16(const short* g, short* l) {
    __builtin_amdgcn_global_load_lds(
        (const __attribute__((address_space(1))) void*)g,
        (__attribute__((address_space(3))) void*)l, 16, 0, 0);
}

// ---------------------------------------------------------------------------
// weights fp32 -> bf16: [pw][Wco][Wq][Wk][Wv][Wck padded to 128x512] and
// tail: dwT[k][c] fp32 transpose of dw_w. grid = 690 blocks.
// ---------------------------------------------------------------------------
__global__ __launch_bounds__(256) void cvt_w_kernel(
    const float* __restrict__ pw, const float* __restrict__ Wco,
    const float* __restrict__ Wq, const float* __restrict__ Wk,
    const float* __restrict__ Wv, const float* __restrict__ Wck,
    const float* __restrict__ dw,
    short* __restrict__ dst, float* __restrict__ dwT)
{
    int idx = blockIdx.x * 256 + threadIdx.x;
    if (idx >= 172032) {                 // dwT tail: 4608 scalar elements
        int t = idx - 172032;
        if (t < AD * KW) {
            int c = t / KW, k = t - c * KW;
            dwT[k * AD + c] = dw[t];
        }
        return;
    }
    int e0 = idx * 8;
    short8 o;
    if (e0 < 5 * WSZ) {
        int w = e0 >> 18, off = e0 & (WSZ - 1);
        const float* src = (w == 0) ? pw : (w == 1) ? Wco : (w == 2) ? Wq
                         : (w == 3) ? Wk : Wv;
        float4 a = *(const float4*)(src + off), c = *(const float4*)(src + off + 4);
        o[0]=f2bf(a.x); o[1]=f2bf(a.y); o[2]=f2bf(a.z); o[3]=f2bf(a.w);
        o[4]=f2bf(c.x); o[5]=f2bf(c.y); o[6]=f2bf(c.z); o[7]=f2bf(c.w);
    } else {
        int off = e0 - 5 * WSZ;          // 0 .. 65535 over 128x512
        int row = off >> 9, col = off & 511;
        if (row < NH * KW) {
            const float* src = Wck + row * AD + col;
            float4 a = *(const float4*)src, c = *(const float4*)(src + 4);
            o[0]=f2bf(a.x); o[1]=f2bf(a.y); o[2]=f2bf(a.z); o[3]=f2bf(a.w);
            o[4]=f2bf(c.x); o[5]=f2bf(c.y); o[6]=f2bf(c.z); o[7]=f2bf(c.w);
        } else {
            for (int i = 0; i < 8; ++i) o[i] = 0;
        }
    }
    *(short8*)(dst + e0) = o;
}

// ---------------------------------------------------------------------------
// Fused: hs fp32 -> bf16 (hsb) AND depthwise conv -> x1 (conv half only).
// One thread = 8 consecutive channels of one token. Center tap reuses the
// registers already loaded for the conversion; 8 neighbor taps read fp32
// (L2-resident). Requires dwT (cvt_w) to have run first.
// ---------------------------------------------------------------------------
__global__ __launch_bounds__(256) void cvt_dw_kernel(
    const float* __restrict__ hs, const float* __restrict__ dwT,
    short* __restrict__ hsb, short* __restrict__ x1)
{
    int idx = blockIdx.x * 256 + threadIdx.x;   // over MTOK*HIDD/8
    int c8  = (idx & 127) * 8;
    int tok = idx >> 7;
    const float* s = hs + (long)tok * HIDD + c8;
    float4 a = *(const float4*)s, c = *(const float4*)(s + 4);
    short8 o;
    o[0]=f2bf(a.x); o[1]=f2bf(a.y); o[2]=f2bf(a.z); o[3]=f2bf(a.w);
    o[4]=f2bf(c.x); o[5]=f2bf(c.y); o[6]=f2bf(c.z); o[7]=f2bf(c.w);
    *(short8*)(hsb + (long)tok * HIDD + c8) = o;

    if (c8 >= AD) {                              // conv half: dwconv
        int cc = c8 - AD;
        int ss = tok & (SS - 1), b = tok >> 11;
        float acc[8];
        {   // center tap (kk=4) from registers
            const float* w0 = dwT + 4 * AD + cc;
            acc[0] = w0[0]*a.x; acc[1] = w0[1]*a.y;
            acc[2] = w0[2]*a.z; acc[3] = w0[3]*a.w;
            acc[4] = w0[4]*c.x; acc[5] = w0[5]*c.y;
            acc[6] = w0[6]*c.z; acc[7] = w0[7]*c.w;
        }
#pragma unroll
        for (int kk = 0; kk < KW; ++kk) {
            if (kk == 4) continue;
            int ss2 = ss + kk - KW / 2;
            if (ss2 >= 0 && ss2 < SS) {
                const float* src = hs + ((long)(b * SS + ss2)) * HIDD + c8;
                float4 h0 = *(const float4*)src, h1 = *(const float4*)(src + 4);
                const float* w0 = dwT + kk * AD + cc;
                acc[0] += w0[0]*h0.x; acc[1] += w0[1]*h0.y;
                acc[2] += w0[2]*h0.z; acc[3] += w0[3]*h0.w;
                acc[4] += w0[4]*h1.x; acc[5] += w0[5]*h1.y;
                acc[6] += w0[6]*h1.z; acc[7] += w0[7]*h1.w;
            }
        }
        short8 ov;
#pragma unroll
        for (int i = 0; i < 8; ++i) ov[i] = f2bf(acc[i]);
        *(short8*)(x1 + (long)tok * AD + cc) = ov;
    }
}

// ---------------------------------------------------------------------------
// bf16 MFMA GEMM, templated wave-tile. BK=64, global_load_lds(16B) staging,
// XOR granule swizzle gk = p ^ (m&7).
// MODE 0: fp32 out, bias b0.  MODE 1: bf16 out, bias b0, *oscale.
// MODE 2: bf16 out, bias b0, * bf16 mulp[m*mul_ld+mul_off+n].
// MODE 3: qkv fused (N=1536): n<512 q (bias b0, *oscale); 512..1023 k
//         (bias b1); n>=1024 V -> vT[b][h][d][s'] permuted key order.
// ---------------------------------------------------------------------------
template<int FM, int FN, int MODE>
__global__ __launch_bounds__(256) void gemm_bf16_kernel(
    const short* __restrict__ X, int ldx, int xoff,
    const short* __restrict__ W,
    const float* __restrict__ b0p, const float* __restrict__ b1p,
    const float* __restrict__ b2p,
    const short* __restrict__ mulp, int mul_ld, int mul_off,
    void* __restrict__ Cout, short* __restrict__ vtout,
    int ldc, int N, int Kd, float oscale)
{
    constexpr int TM = 32 * FM, TN = 32 * FN;
    __shared__ __align__(16) short As[TM * 64];
    __shared__ __align__(16) short Bs[TN * 64];
    const int tid  = threadIdx.x;
    const int wv   = tid >> 6, lane = tid & 63;
    const int ln   = lane & 15, quad = lane >> 4;
    const int wm   = wv >> 1, wn = wv & 1;
    const int m0 = blockIdx.x * TM, n0 = blockIdx.y * TN;

    floatx4 acc[FM][FN];
#pragma unroll
    for (int i = 0; i < FM; ++i)
#pragma unroll
        for (int j = 0; j < FN; ++j) acc[i][j] = (floatx4){0.f, 0.f, 0.f, 0.f};

    const short* xbase = X + (long)m0 * ldx + xoff;
    const short* wbase = W + (long)n0 * Kd;

    for (int k0 = 0; k0 < Kd; k0 += 64) {
#pragma unroll
        for (int g = tid; g < TM * 8; g += 256) {
            int m = g >> 3, p = g & 7, gk = p ^ (m & 7);
            gl2lds16(xbase + (long)m * ldx + k0 + gk * 8, &As[g * 8]);
        }
#pragma unroll
        for (int g = tid; g < TN * 8; g += 256) {
            int m = g >> 3, p = g & 7, gk = p ^ (m & 7);
            gl2lds16(wbase + (long)m * Kd + k0 + gk * 8, &Bs[g * 8]);
        }
        __syncthreads();
#pragma unroll
        for (int half = 0; half < 2; ++half) {
            short8 afr[FM], bfr[FN];
#pragma unroll
            for (int i = 0; i < FM; ++i) {
                int p = (half * 4 + quad) ^ (ln & 7);
                afr[i] = *(const short8*)&As[(wm * 16 * FM + i * 16 + ln) * 64 + p * 8];
            }
#pragma unroll
            for (int j = 0; j < FN; ++j) {
                int p = (half * 4 + quad) ^ (ln & 7);
                bfr[j] = *(const short8*)&Bs[(wn * 16 * FN + j * 16 + ln) * 64 + p * 8];
            }
#pragma unroll
            for (int i = 0; i < FM; ++i)
#pragma unroll
                for (int j = 0; j < FN; ++j)
                    acc[i][j] = __builtin_amdgcn_mfma_f32_16x16x32_bf16(
                        afr[i], bfr[j], acc[i][j], 0, 0, 0);
        }
        __syncthreads();
    }

#pragma unroll
    for (int j = 0; j < FN; ++j) {
        int n = n0 + wn * 16 * FN + j * 16 + ln;
        if constexpr (MODE == 3) {
            if (n >= 1024) {
                // V third -> vT (permuted key order), 8B packed stores
                int hh = (n - 1024) >> 6, dd = (n - 1024) & 63;
                float bv = b2p[n - 1024];
                int mblk = m0 + wm * 16 * FM;             // 64-aligned (FM=4)
                int bidx = mblk >> 11, sblk = mblk & (SS - 1);
                short* dst = vtout + ((long)((bidx * NH + hh) * HD + dd)) * SS + sblk;
#pragma unroll
                for (int r = 0; r < 4; ++r) {
                    unsigned lo = pkbf2(acc[0][j][r] + bv, acc[1 % FM][j][r] + bv);
                    unsigned hi = pkbf2(acc[2 % FM][j][r] + bv, acc[3 % FM][j][r] + bv);
                    *(uint2*)(dst + (quad * 4 + r) * 4) = make_uint2(lo, hi);
                }
            } else {
                float bv = (n < 512) ? b0p[n] : b1p[n - 512];
                float sc = (n < 512) ? oscale : 1.f;
#pragma unroll
                for (int i = 0; i < FM; ++i) {
#pragma unroll
                    for (int r = 0; r < 4; ++r) {
                        int m = m0 + wm * 16 * FM + i * 16 + quad * 4 + r;
                        float val = (acc[i][j][r] + bv) * sc;
                        ((short*)Cout)[(long)m * ldc + n] = f2bf(val);
                    }
                }
            }
        } else if (n < N) {
            float bv = b0p[n], sc = oscale;
#pragma unroll
            for (int i = 0; i < FM; ++i) {
#pragma unroll
                for (int r = 0; r < 4; ++r) {
                    int m = m0 + wm * 16 * FM + i * 16 + quad * 4 + r;
                    float val = (acc[i][j][r] + bv) * sc;
                    if constexpr (MODE == 2)
                        val *= bf2f(mulp[(long)m * mul_ld + mul_off + n]);
                    if constexpr (MODE == 0)
                        ((float*)Cout)[(long)m * ldc + n] = val;
                    else
                        ((short*)Cout)[(long)m * ldc + n] = f2bf(val);
                }
            }
        }
    }
}

// ---------------------------------------------------------------------------
// conv_out, 4 channels/thread: out[b,s,h,d4..d4+3] =
//   sum_k col[b,s+k-4,h*64+d4..] * softmax9(logits[b,s,h,:])[k]
// ---------------------------------------------------------------------------
__global__ __launch_bounds__(256) void convout_kernel(
    const short* __restrict__ col, const float* __restrict__ ckl,
    float* __restrict__ out)
{
    int idx = blockIdx.x * 256 + threadIdx.x;   // over MTOK*AD/4
    int d4  = (idx & 127) * 4;                  // channel quad (0..508)
    int tok = idx >> 7;
    int s   = tok & (SS - 1);
    int b   = tok >> 11;
    int h   = d4 >> 6;
    const float* lg = ckl + (long)tok * (NH * KW) + h * KW;
    float wv[KW];
    float mx = -1e30f;
#pragma unroll
    for (int i = 0; i < KW; ++i) { wv[i] = lg[i]; mx = fmaxf(mx, wv[i]); }
    float sum = 0.f;
#pragma unroll
    for (int i = 0; i < KW; ++i) { wv[i] = __expf(wv[i] - mx); sum += wv[i]; }
    float inv = 1.f / sum;
    float a0 = 0.f, a1 = 0.f, a2 = 0.f, a3 = 0.f;
    const short* cbase = col + (long)(b * SS) * AD + d4;
#pragma unroll
    for (int kk = 0; kk < KW; ++kk) {
        int ss2 = s + kk - KW / 2;
        if (ss2 >= 0 && ss2 < SS) {
            uint2 cv = *(const uint2*)(cbase + (long)ss2 * AD);
            float w = wv[kk];
            a0 += w * bf2f((short)(cv.x & 0xFFFF));
            a1 += w * bf2f((short)(cv.x >> 16));
            a2 += w * bf2f((short)(cv.y & 0xFFFF));
            a3 += w * bf2f((short)(cv.y >> 16));
        }
    }
    *(float4*)&out[(long)tok * HIDD + AD + d4] =
        make_float4(a0 * inv, a1 * inv, a2 * inv, a3 * inv);
}

// ---------------------------------------------------------------------------
// MFMA flash attention v4: 32 q-rows per wave (2 row-subtiles sharing K/V
// fragment reads), 128 q-rows per block. q pre-scaled log2(e)/8 -> exp2.
// No max-tracking. Keys permuted within each 64-block (p=(k&15)*4+(k>>4));
// P written packed (1 ds_write_b64/row); vT pre-permuted by the qkv GEMM.
// ---------------------------------------------------------------------------
__global__ __launch_bounds__(256) void flash_mfma_kernel(
    const short* __restrict__ qkv, const short* __restrict__ vT,
    float* __restrict__ out)
{
    const int qt = blockIdx.x, h = blockIdx.y, b = blockIdx.z;
    const int tid  = threadIdx.x;
    const int w    = tid >> 6;        // wave 0..3
    const int lane = tid & 63;
    const int ln   = lane & 15;
    const int quad = lane >> 4;

    __shared__ __align__(16) short Kb[64 * 64];     // [key][d] (swizzled)
    __shared__ __align__(16) short Vt[64 * 64];     // [d][key'] (swizzled)
    __shared__ __align__(16) short Ps[4][32 * 72];  // per-wave [qrow][key']

    const int  q0 = qt * 128;
    const long rowbase = (long)b * SS;

    short8 qa[2][2];
#pragma unroll
    for (int u = 0; u < 2; ++u) {
        const short* qrow = qkv + (rowbase + q0 + w * 32 + u * 16 + ln) * 1536 + h * HD;
        qa[u][0] = *(const short8*)(qrow + quad * 8);
        qa[u][1] = *(const short8*)(qrow + 32 + quad * 8);
    }

    floatx4 acc[2][4];
    float l_i[2][4];
#pragma unroll
    for (int u = 0; u < 2; ++u)
#pragma unroll
        for (int r = 0; r < 4; ++r) {
            l_i[u][r] = 0.f;
            acc[u][r] = (floatx4){0.f, 0.f, 0.f, 0.f};
        }

    const short* kbase  = qkv + 512 + rowbase * 1536 + h * HD;
    const short* vtbase = vT + ((long)(b * NH + h) * HD) * SS;
    const int p0i = quad ^ (ln & 7), p1i = (4 + quad) ^ (ln & 7);

    for (int kt = 0; kt < SS / 64; ++kt) {
        const int k0 = kt * 64;
#pragma unroll
        for (int it = 0; it < 2; ++it) {
            int g = it * 256 + tid;
            int m = g >> 3, p = g & 7, gk = p ^ (m & 7);
            gl2lds16(kbase + (long)(k0 + m) * 1536 + gk * 8, &Kb[g * 8]);
        }
#pragma unroll
        for (int it = 0; it < 2; ++it) {
            int g = it * 256 + tid;
            int m = g >> 3, p = g & 7, gk = p ^ (m & 7);
            gl2lds16(vtbase + (long)m * SS + k0 + gk * 8, &Vt[g * 8]);
        }
        __syncthreads();

        // ---- S = Q K^T : K frags shared across both row-subtiles ----
        floatx4 S[2][4];
#pragma unroll
        for (int st = 0; st < 4; ++st) {
            short8 b0 = *(const short8*)&Kb[(st * 16 + ln) * 64 + p0i * 8];
            short8 b1 = *(const short8*)&Kb[(st * 16 + ln) * 64 + p1i * 8];
#pragma unroll
            for (int u = 0; u < 2; ++u) {
                floatx4 z = (floatx4){0.f, 0.f, 0.f, 0.f};
                z = __builtin_amdgcn_mfma_f32_16x16x32_bf16(qa[u][0], b0, z, 0, 0, 0);
                S[u][st] = __builtin_amdgcn_mfma_f32_16x16x32_bf16(qa[u][1], b1, z, 0, 0, 0);
            }
        }

        // ---- p = exp2(s'), partial l, packed P -> LDS at key' = ln*4+st ----
#pragma unroll
        for (int u = 0; u < 2; ++u)
#pragma unroll
            for (int r = 0; r < 4; ++r) {
                float p0 = exp2_raw(S[u][0][r]);
                float p1 = exp2_raw(S[u][1][r]);
                float p2 = exp2_raw(S[u][2][r]);
                float p3 = exp2_raw(S[u][3][r]);
                l_i[u][r] += (p0 + p1) + (p2 + p3);
                unsigned lo = pkbf2(p0, p1);
                unsigned hi = pkbf2(p2, p3);
                *(uint2*)&Ps[w][(u * 16 + quad * 4 + r) * 72 + ln * 4] =
                    make_uint2(lo, hi);
            }

        // ---- ctx += P V : V frags shared across both row-subtiles ----
        {
            short8 pa[2][2];
#pragma unroll
            for (int u = 0; u < 2; ++u) {
                pa[u][0] = *(const short8*)&Ps[w][(u * 16 + ln) * 72 + quad * 8];
                pa[u][1] = *(const short8*)&Ps[w][(u * 16 + ln) * 72 + 32 + quad * 8];
            }
#pragma unroll
            for (int st = 0; st < 4; ++st) {
                short8 vb0 = *(const short8*)&Vt[(st * 16 + ln) * 64 + p0i * 8];
                short8 vb1 = *(const short8*)&Vt[(st * 16 + ln) * 64 + p1i * 8];
#pragma unroll
                for (int u = 0; u < 2; ++u) {
                    acc[u][st] = __builtin_amdgcn_mfma_f32_16x16x32_bf16(pa[u][0], vb0, acc[u][st], 0, 0, 0);
                    acc[u][st] = __builtin_amdgcn_mfma_f32_16x16x32_bf16(pa[u][1], vb1, acc[u][st], 0, 0, 0);
                }
            }
        }
        __syncthreads();
    }

    // final l reduction + store
#pragma unroll
    for (int u = 0; u < 2; ++u)
#pragma unroll
        for (int r = 0; r < 4; ++r) {
#pragma unroll
            for (int off = 1; off < 16; off <<= 1)
                l_i[u][r] += __shfl_xor(l_i[u][r], off);
            float inv = 1.f / l_i[u][r];
            float* orow = out + (rowbase + q0 + w * 32 + u * 16 + quad * 4 + r) * HIDD + h * HD;
#pragma unroll
            for (int st = 0; st < 4; ++st)
                orow[st * 16 + ln] = acc[u][st][r] * inv;
        }
}

// ---------------------------------------------------------------------------
extern "C" void kernel_launch(void* const* d_in, const int* in_sizes, int n_in,
                              void* d_out, int out_size, void* d_ws, size_t ws_size,
                              hipStream_t stream)
{
    const float* hs   = (const float*)d_in[0];
    const float* Wq   = (const float*)d_in[1];
    const float* bq   = (const float*)d_in[2];
    const float* Wk   = (const float*)d_in[3];
    const float* bk   = (const float*)d_in[4];
    const float* Wv   = (const float*)d_in[5];
    const float* bv   = (const float*)d_in[6];
    const float* dw   = (const float*)d_in[7];
    const float* pw   = (const float*)d_in[8];
    const float* sepb = (const float*)d_in[9];
    const float* Wck  = (const float*)d_in[10];
    const float* bck  = (const float*)d_in[11];
    const float* Wco  = (const float*)d_in[12];
    const float* bco  = (const float*)d_in[13];
    float* out = (float*)d_out;

    // workspace (bf16 shorts unless noted)
    short* hsb  = (short*)d_ws;                       // MTOK x 1024
    short* x1c  = hsb + (long)MTOK * HIDD;            // MTOK x 512 (x1, then col)
    short* qkvb = x1c + (long)MTOK * AD;              // MTOK x 1536 (conv_attn first)
    short* vTb  = qkvb + (long)MTOK * 1536;           // [b][h][d][s'] MTOK*512
    float* ckl  = (float*)(vTb + (long)MTOK * AD);    // MTOK x 72 fp32 logits
    short* wb   = (short*)(ckl + (long)MTOK * (NH * KW));
    short* pw_b   = wb;
    short* Wco_b  = wb + 1L * WSZ;
    short* Wqkv_b = wb + 2L * WSZ;                    // [Wq;Wk;Wv] 1536 x 512
    short* Wck_b  = wb + 5L * WSZ;                    // 128 x 512 (padded)
    float* dwT    = (float*)(Wck_b + 128L * AD);      // [9][512] fp32
    short* cab    = qkvb;                             // conv_attn alias

    const float QSCALE = 0.18033688011112042f;        // log2(e)/8

    // 1. weight conversions (+dwT transpose tail) — must precede cvt_dw
    cvt_w_kernel<<<690, 256, 0, stream>>>(
        pw, Wco, Wq, Wk, Wv, Wck, dw, wb, dwT);
    // 2. fused hs->bf16 + depthwise conv -> hsb, x1
    cvt_dw_kernel<<<MTOK * HIDD / 2048, 256, 0, stream>>>(hs, dwT, hsb, x1c);
    // 3. pointwise: conv_attn = (x1 @ pw^T + sep_b) * hs_conv (bf16 mulp)
    gemm_bf16_kernel<2, 2, 2><<<dim3(MTOK / 64, AD / 64), 256, 0, stream>>>(
        x1c, AD, 0, pw_b, sepb, nullptr, nullptr, hsb, HIDD, AD,
        cab, nullptr, AD, AD, AD, 1.f);
    // 4. ckl logits = conv_attn @ Wck^T + bck  (N=72, fp32 out)
    gemm_bf16_kernel<2, 2, 0><<<dim3(MTOK / 64, 2), 256, 0, stream>>>(
        cab, AD, 0, Wck_b, bck, nullptr, nullptr, nullptr, 0, 0,
        ckl, nullptr, NH * KW, NH * KW, AD, 1.f);
    // 5. col = hs_conv @ Wco^T + bco -> x1c (x1 dead)
    gemm_bf16_kernel<2, 2, 1><<<dim3(MTOK / 64, AD / 64), 256, 0, stream>>>(
        hsb, HIDD, AD, Wco_b, bco, nullptr, nullptr, nullptr, 0, 0,
        x1c, nullptr, AD, AD, AD, 1.f);
    // 6. windowed mix w/ fused softmax9 -> out[..., 512:] (4 ch/thread)
    convout_kernel<<<MTOK * AD / 1024, 256, 0, stream>>>(x1c, ckl, out);
    // 7. fused qkv projection; q pre-scaled log2(e)/8; V -> vT (permuted)
    gemm_bf16_kernel<4, 4, 3><<<dim3(MTOK / 128, 1536 / 128), 256, 0, stream>>>(
        hsb, HIDD, 0, Wqkv_b, bq, bk, bv, nullptr, 0, 0,
        qkvb, vTb, 1536, 1536, AD, QSCALE);
    // 8. attention -> out[..., :512]  (128 q-rows per block)
    flash_mfma_kernel<<<dim3(SS / 128, NH, BB), 256, 0, stream>>>(qkvb, vTb, out);

    (void)in_sizes; (void)n_in; (void)out_size; (void)ws_size;
}